// Round 1
// 243.104 us; speedup vs baseline: 1.0341x; 1.0341x over previous
//
#include <hip/hip_runtime.h>

#define TT 2048
#define CC 1024

typedef __attribute__((ext_vector_type(8))) __bf16 bf16x8;
typedef __attribute__((ext_vector_type(4))) float f32x4;
typedef unsigned int u32;

__device__ __forceinline__ short f2bf(float f) {
  u32 u = __float_as_uint(f);
  u += 0x7fffu + ((u >> 16) & 1u);  // RTNE
  return (short)(u >> 16);
}

#if __has_builtin(__builtin_amdgcn_cvt_pk_bf16_f32)
__device__ __forceinline__ u32 pack2(float a, float b) {
  auto v = __builtin_amdgcn_cvt_pk_bf16_f32(a, b);
  return __builtin_bit_cast(u32, v);
}
#else
__device__ __forceinline__ u32 pack2(float a, float b) {
  u32 ua = __float_as_uint(a), ub = __float_as_uint(b);
  ua += 0x7fffu + ((ua >> 16) & 1u);
  ub += 0x7fffu + ((ub >> 16) & 1u);
  return (ua >> 16) | (ub & 0xffff0000u);
}
#endif

// ---------------- fused fp32 -> bf16 cast (x | wqkv(Q scaled) | wout) ---------
__global__ __launch_bounds__(256) void cvt_all(const float* __restrict__ x,
                                               const float* __restrict__ wqkv,
                                               const float* __restrict__ wout,
                                               short* __restrict__ dst) {
  int i = blockIdx.x * blockDim.x + threadIdx.x;  // float4 index, < 3145728
  const float* src;
  float sc = 1.0f;
  if (i < 2097152) {
    src = x + (size_t)i * 4;
  } else if (i < 2883584) {
    int j = i - 2097152;
    src = wqkv + (size_t)j * 4;
    if (j < 262144) sc = 0.125f;  // Q block: fold attention scale (exact pow2)
  } else {
    src = wout + (size_t)(i - 2883584) * 4;
  }
  float4 f = *reinterpret_cast<const float4*>(src);
  short4 s;
  s.x = f2bf(f.x * sc); s.y = f2bf(f.y * sc); s.z = f2bf(f.z * sc); s.w = f2bf(f.w * sc);
  reinterpret_cast<short4*>(dst)[i] = s;
}

__device__ __forceinline__ void storev(float* p, float v) { *p = v; }
__device__ __forceinline__ void storev(short* p, float v) { *p = f2bf(v); }

#if __has_builtin(__builtin_amdgcn_global_load_lds)
#define HAVE_GLD_LDS 1
__device__ __forceinline__ void gld_lds16(const short* g, short* l) {
  __builtin_amdgcn_global_load_lds((const __attribute__((address_space(1))) u32*)g,
                                   (__attribute__((address_space(3))) u32*)l, 16, 0, 0);
}
#endif

__device__ __forceinline__ f32x4 mfma16(bf16x8 a, bf16x8 b, f32x4 c) {
  return __builtin_amdgcn_mfma_f32_16x16x32_bf16(a, b, c, 0, 0, 0);
}

template <int MH>
__device__ __forceinline__ void mma4x4(f32x4 (&acc)[8][4], const bf16x8 (&af)[4],
                                       const bf16x8 (&bfr)[4]) {
#pragma unroll
  for (int mf = 0; mf < 4; ++mf)
#pragma unroll
    for (int nf = 0; nf < 4; ++nf)
      acc[MH * 4 + mf][nf] = mfma16(af[mf], bfr[nf], acc[MH * 4 + mf][nf]);
}

// =================== C[M,N] = A[M,K] * B[N,K]^T, 256x256 8-phase ==============
// 512 thr = 8 waves (2M x 4N), BK=64, LDS 128 KiB: 2 dbuf x {A,B} x 2 k-panels
// of [256][32] shorts (64B rows). k-slot XOR swizzle (slot ^= (row>>1)&3) via
// pre-swizzled GLOBAL source + linear global_load_lds dest; ds_read_b128 then
// lands 2 dwords/bank/quarter-wave = conflict-free.
// Schedule (phases P1..P8 per iteration = 2 K-tiles; tile t -> buf[t&1]):
//   P1 rd(b0,ks0,mh0)+B   stage b1.A_khi(2i+1)
//   P2 rd(b0,ks0,mh1)     stage b0.B_klo(2i+2)
//   P3 rd(b0,ks1,mh0)+B   stage b0.A_klo(2i+2)
//   P4 rd(b0,ks1,mh1)     stage b0.B_khi(2i+2)   vmcnt(6)
//   P5 rd(b1,ks0,mh0)+B   stage b0.A_khi(2i+2)
//   P6 rd(b1,ks0,mh1)     stage b1.B_klo(2i+3)
//   P7 rd(b1,ks1,mh0)+B   stage b1.A_klo(2i+3)
//   P8 rd(b1,ks1,mh1)     stage b1.B_khi(2i+3)   vmcnt(6)
// Each stage target's last ds_read is in the previous phase (drained by that
// phase's lgkmcnt(0)+barrier); each consumed tile's last half is staged 3
// stage-slots (=6 loads) before its vmcnt(6). Every phase carries a
// memory-clobber asm, so VMEM issue stays phase-accurate for the counting.
#define GPHASE(DB, KS, MH, LOADB, STG, SYNC)               \
  {                                                        \
    ldA(af, DB, KS, MH);                                   \
    if (LOADB) ldB(bfr, DB, KS);                           \
    STG;                                                   \
    __builtin_amdgcn_s_barrier();                          \
    asm volatile("s_waitcnt lgkmcnt(0)" ::: "memory");     \
    __builtin_amdgcn_sched_barrier(0);                     \
    __builtin_amdgcn_s_setprio(1);                         \
    mma4x4<MH>(acc, af, bfr);                              \
    __builtin_amdgcn_s_setprio(0);                         \
    SYNC;                                                  \
    __builtin_amdgcn_s_barrier();                          \
  }
#define SYNC6 asm volatile("s_waitcnt vmcnt(6)" ::: "memory")
#define SYNC0 asm volatile("s_waitcnt vmcnt(0)" ::: "memory")
#define GNOOP ((void)0)

template <typename OutT, int N, int K>
__global__ __launch_bounds__(512, 2) void gemm256(const short* __restrict__ A,
                                                  const short* __restrict__ B,
                                                  OutT* __restrict__ Cm) {
  extern __shared__ short lds[];  // 65536 shorts = 128 KiB
  constexpr int NT = K / 64;       // K-tiles (16 for K=1024)
  constexpr int NITER = NT / 2;
  constexpr int NWG = (N / 256) * 32;  // grid = (32, N/256); both %8 == 0
  const int tid = threadIdx.x;
  const int wave = tid >> 6, lane = tid & 63;
  const int quad = lane >> 4, nl = lane & 15;
  const int wm = wave >> 2, wn = wave & 3;

  // bijective XCD swizzle on linear tile id
  int id = blockIdx.y * 32 + blockIdx.x;
  id = (id & 7) * (NWG / 8) + (id >> 3);
  const int m0 = (id & 31) * 256, n0 = (id >> 5) * 256;

  // stage source: wave w owns rows [w*32, w*32+32); lane -> (row = L>>2, slot
  // permuted (L&3)^((L>>3)&3)); permutation stays inside 64B segs (coalesced).
  const int srow = lane >> 2;
  const int sperm = ((lane & 3) ^ ((lane >> 3) & 3)) * 8;
  const short* pA = A + (size_t)(m0 + wave * 32 + srow) * K + sperm;
  const short* pB = B + (size_t)(n0 + wave * 32 + srow) * K + sperm;
  short* dstA = lds + wave * 1024;
  short* dstB = lds + 16384 + wave * 1024;

  // frag read: LDS(row, slot_lin) holds global slot (slot_lin ^ ((row>>1)&3))
  const int perm = (quad ^ ((nl >> 1) & 3)) * 8;
  const int aoff = (wm * 128 + nl) * 32 + perm;
  const int boff = (wn * 64 + nl) * 32 + perm;

  f32x4 acc[8][4] = {};

  auto stageA = [&](int db, int ks, int t) {
    const short* s = pA + (size_t)t * 64 + ks * 32;
    short* d = dstA + db * 32768 + ks * 8192;
#if HAVE_GLD_LDS
    gld_lds16(s, d);
    gld_lds16(s + (size_t)16 * K, d + 512);
#else
    *reinterpret_cast<uint4*>(d + lane * 8) = *reinterpret_cast<const uint4*>(s);
    *reinterpret_cast<uint4*>(d + 512 + lane * 8) =
        *reinterpret_cast<const uint4*>(s + (size_t)16 * K);
#endif
  };
  auto stageB = [&](int db, int ks, int t) {
    const short* s = pB + (size_t)t * 64 + ks * 32;
    short* d = dstB + db * 32768 + ks * 8192;
#if HAVE_GLD_LDS
    gld_lds16(s, d);
    gld_lds16(s + (size_t)16 * K, d + 512);
#else
    *reinterpret_cast<uint4*>(d + lane * 8) = *reinterpret_cast<const uint4*>(s);
    *reinterpret_cast<uint4*>(d + 512 + lane * 8) =
        *reinterpret_cast<const uint4*>(s + (size_t)16 * K);
#endif
  };
  auto ldA = [&](bf16x8 (&af)[4], int db, int ks, int mh) {
#pragma unroll
    for (int mf = 0; mf < 4; ++mf)
      af[mf] = *reinterpret_cast<const bf16x8*>(
          &lds[db * 32768 + ks * 8192 + aoff + (mh * 4 + mf) * 512]);
  };
  auto ldB = [&](bf16x8 (&bfr)[4], int db, int ks) {
#pragma unroll
    for (int nf = 0; nf < 4; ++nf)
      bfr[nf] = *reinterpret_cast<const bf16x8*>(
          &lds[db * 32768 + 16384 + ks * 8192 + boff + nf * 512]);
  };

  // prologue: tile0 fully + tile1 {B_klo, A_klo, B_khi} (A_khi comes at P1)
  stageA(0, 0, 0); stageA(0, 1, 0); stageB(0, 0, 0); stageB(0, 1, 0);
  stageB(1, 0, 1); stageA(1, 0, 1); stageB(1, 1, 1);
  asm volatile("s_waitcnt vmcnt(6)" ::: "memory");  // 14 issued; tile0 landed
  __builtin_amdgcn_s_barrier();

  for (int i = 0; i < NITER - 1; ++i) {
    const int to1 = 2 * i + 1, te2 = 2 * i + 2, to3 = 2 * i + 3;
    bf16x8 af[4], bfr[4];
    GPHASE(0, 0, 0, 1, stageA(1, 1, to1), GNOOP)
    GPHASE(0, 0, 1, 0, stageB(0, 0, te2), GNOOP)
    GPHASE(0, 1, 0, 1, stageA(0, 0, te2), GNOOP)
    GPHASE(0, 1, 1, 0, stageB(0, 1, te2), SYNC6)
    GPHASE(1, 0, 0, 1, stageA(0, 1, te2), GNOOP)
    GPHASE(1, 0, 1, 0, stageB(1, 0, to3), GNOOP)
    GPHASE(1, 1, 0, 1, stageA(1, 0, to3), GNOOP)
    GPHASE(1, 1, 1, 0, stageB(1, 1, to3), SYNC6)
  }
  {  // last iteration: only tile NT-1's A_khi still needs staging
    bf16x8 af[4], bfr[4];
    GPHASE(0, 0, 0, 1, stageA(1, 1, NT - 1), GNOOP)
    GPHASE(0, 0, 1, 0, GNOOP, GNOOP)
    GPHASE(0, 1, 0, 1, GNOOP, GNOOP)
    GPHASE(0, 1, 1, 0, GNOOP, SYNC0)
    GPHASE(1, 0, 0, 1, GNOOP, GNOOP)
    GPHASE(1, 0, 1, 0, GNOOP, GNOOP)
    GPHASE(1, 1, 0, 1, GNOOP, GNOOP)
    GPHASE(1, 1, 1, 0, GNOOP, GNOOP)
  }

#pragma unroll
  for (int mf = 0; mf < 8; ++mf) {
    const int row = m0 + wm * 128 + mf * 16 + quad * 4;
#pragma unroll
    for (int nf = 0; nf < 4; ++nf) {
      const int col = n0 + wn * 64 + nf * 16 + nl;
#pragma unroll
      for (int r = 0; r < 4; ++r)
        storev(&Cm[(size_t)(row + r) * N + col], acc[mf][nf][r]);
    }
  }
}

// ---------------- V transpose: qkv V-part -> Vt[bh][d][t] ---------------------
__global__ __launch_bounds__(256) void transpose_v(const short* __restrict__ qkv,
                                                   short* __restrict__ vt) {
  __shared__ short Ls[64 * 68];
  const int bh = blockIdx.y, tb = blockIdx.x;
  const int b = bh >> 4, h = bh & 15;
  const int tid = threadIdx.x;
  const short* src = qkv + (size_t)(b * TT + tb * 64) * (3 * CC) + 2 * CC + h * 64;
#pragma unroll
  for (int i = 0; i < 2; ++i) {
    int idx = tid + i * 256;
    int tl = idx >> 3, dc = idx & 7;
    uint4 d4 = *reinterpret_cast<const uint4*>(&src[(size_t)tl * (3 * CC) + dc * 8]);
    *reinterpret_cast<uint2*>(&Ls[tl * 68 + dc * 8]) = make_uint2(d4.x, d4.y);
    *reinterpret_cast<uint2*>(&Ls[tl * 68 + dc * 8 + 4]) = make_uint2(d4.z, d4.w);
  }
  __syncthreads();
  short* dst = vt + (size_t)(bh * 64) * TT + tb * 64;
#pragma unroll
  for (int i = 0; i < 2; ++i) {
    int idx = tid + i * 256;
    int dl = idx >> 3, tc = idx & 7;
    short tmp[8];
#pragma unroll
    for (int j = 0; j < 8; ++j) tmp[j] = Ls[(tc * 8 + j) * 68 + dl];
    *reinterpret_cast<uint4*>(&dst[(size_t)dl * TT + tc * 8]) = *reinterpret_cast<uint4*>(tmp);
  }
}

// ---------------- attention compute (one 32-col half-chunk, one wave) ---------
template <bool DIAG>
__device__ __forceinline__ void attn_compute(const short* kf, const short* vf, u32* ssw,
                                             const bf16x8 (&qf)[2][2], f32x4 (&o)[2][4],
                                             int lane, int quad, int nl) {
  bf16x8 k00 = *reinterpret_cast<const bf16x8*>(&kf[0 * 512 + lane * 8]);
  bf16x8 k01 = *reinterpret_cast<const bf16x8*>(&kf[1 * 512 + lane * 8]);
  bf16x8 k10 = *reinterpret_cast<const bf16x8*>(&kf[2 * 512 + lane * 8]);
  bf16x8 k11 = *reinterpret_cast<const bf16x8*>(&kf[3 * 512 + lane * 8]);
  bf16x8 vB[4];
#pragma unroll
  for (int nb = 0; nb < 4; ++nb)
    vB[nb] = *reinterpret_cast<const bf16x8*>(&vf[nb * 512 + lane * 8]);
  {
    u32* srow = &ssw[0 * 320 + nl * 20];
    f32x4 s0 = {};
    s0 = mfma16(k00, qf[0][0], s0);
    s0 = mfma16(k01, qf[0][1], s0);
    if (DIAG) {
#pragma unroll
      for (int r = 0; r < 4; ++r) s0[r] = (quad * 4 + r <= nl) ? s0[r] : 0.0f;
    }
#pragma unroll
    for (int p = 0; p < 2; ++p) srow[quad * 2 + p] = pack2(s0[2 * p], s0[2 * p + 1]);
    if (DIAG) {
#pragma unroll
      for (int p = 0; p < 2; ++p) srow[8 + quad * 2 + p] = 0;
    } else {
      f32x4 s1 = {};
      s1 = mfma16(k10, qf[0][0], s1);
      s1 = mfma16(k11, qf[0][1], s1);
#pragma unroll
      for (int p = 0; p < 2; ++p) srow[8 + quad * 2 + p] = pack2(s1[2 * p], s1[2 * p + 1]);
    }
  }
  {
    u32* srow = &ssw[1 * 320 + nl * 20];
    f32x4 s0 = {}, s1 = {};
    s0 = mfma16(k00, qf[1][0], s0);
    s0 = mfma16(k01, qf[1][1], s0);
    s1 = mfma16(k10, qf[1][0], s1);
    s1 = mfma16(k11, qf[1][1], s1);
    if (DIAG) {
#pragma unroll
      for (int r = 0; r < 4; ++r) s1[r] = (quad * 4 + r <= nl) ? s1[r] : 0.0f;
    }
#pragma unroll
    for (int p = 0; p < 2; ++p) {
      srow[quad * 2 + p] = pack2(s0[2 * p], s0[2 * p + 1]);
      srow[8 + quad * 2 + p] = pack2(s1[2 * p], s1[2 * p + 1]);
    }
  }
#pragma unroll
  for (int m = 0; m < 2; ++m) {
    bf16x8 sf = *reinterpret_cast<const bf16x8*>(&ssw[m * 320 + nl * 20 + quad * 4]);
#pragma unroll
    for (int nb = 0; nb < 4; ++nb) o[m][nb] = mfma16(sf, vB[nb], o[m][nb]);
  }
}

// ---------------- causal masked attention (no softmax) ------------------------
__global__ __launch_bounds__(256, 3) void attn_kernel(const short* __restrict__ qkv,
                                                      const short* __restrict__ vt,
                                                      short* __restrict__ attnb) {
  const int bh = blockIdx.x;
  const int b = bh >> 4, h = bh & 15;
  const int ti = 15 - blockIdx.y;  // big tiles first
  const int T0 = ti * 128;
  const int tid = threadIdx.x;
  const int wave = tid >> 6, lane = tid & 63;
  const int quad = lane >> 4, nl = lane & 15;

  const short* qbase = qkv + (size_t)(b * TT) * (3 * CC) + h * 64;
  const short* kbase = qbase + CC;
  const short* vbase = vt + (size_t)(bh * 64) * TT;

  __shared__ __align__(16) short Frag[2][8192];  // 2 x 16 KB staged K/V frags
  __shared__ __align__(16) u32 Ss[4][640];       // per-wave S roundtrip (stride 20)
  u32* ssw = Ss[wave];

  const int tw0 = T0 + wave * 32;
  bf16x8 qf[2][2];  // Q B-frags (pre-scaled by 0.125)
#pragma unroll
  for (int m = 0; m < 2; ++m)
#pragma unroll
    for (int half = 0; half < 2; ++half)
      qf[m][half] = *reinterpret_cast<const bf16x8*>(
          &qbase[(size_t)(tw0 + m * 16 + nl) * (3 * CC) + half * 32 + quad * 8]);

  f32x4 o[2][4] = {};

  const short* ksrc = kbase + (size_t)(wave * 16 + nl) * (3 * CC) + quad * 8;
  const int sp_w = wave >> 1, nb0 = (wave & 1) * 2;
  const short* vsrc0 = vbase + (size_t)((nb0 + 0) * 16 + nl) * TT + sp_w * 32 + quad * 8;
  const short* vsrc1 = vbase + (size_t)((nb0 + 1) * 16 + nl) * TT + sp_w * 32 + quad * 8;

  auto stage = [&](short* fb, int c) {
    const size_t koff = (size_t)(c * 64) * (3 * CC);
#if HAVE_GLD_LDS
    gld_lds16(ksrc + koff, &fb[(2 * wave) * 512]);
    gld_lds16(ksrc + koff + 32, &fb[(2 * wave + 1) * 512]);
    gld_lds16(vsrc0 + c * 64, &fb[4096 + (2 * wave) * 512]);
    gld_lds16(vsrc1 + c * 64, &fb[4096 + (2 * wave + 1) * 512]);
#else
    *reinterpret_cast<uint4*>(&fb[(2 * wave) * 512 + lane * 8]) =
        *reinterpret_cast<const uint4*>(ksrc + koff);
    *reinterpret_cast<uint4*>(&fb[(2 * wave + 1) * 512 + lane * 8]) =
        *reinterpret_cast<const uint4*>(ksrc + koff + 32);
    *reinterpret_cast<uint4*>(&fb[4096 + (2 * wave) * 512 + lane * 8]) =
        *reinterpret_cast<const uint4*>(vsrc0 + c * 64);
    *reinterpret_cast<uint4*>(&fb[4096 + (2 * wave + 1) * 512 + lane * 8]) =
        *reinterpret_cast<const uint4*>(vsrc1 + c * 64);
#endif
  };

  const int nch = 2 * ti + 2;     // 64-col chunks
  const int cd = 4 * ti + wave;   // this wave's diagonal 32-chunk index

  stage(Frag[0], 0);
  for (int c = 0; c < nch; ++c) {
    __syncthreads();  // compiler vmcnt(0) here drains stage(c); buf[c&1] ready
    if (c + 1 < nch) stage(Frag[(c + 1) & 1], c + 1);  // overlaps compute below
    const short* fb = Frag[c & 1];
    const int c0 = 2 * c, c1 = 2 * c + 1;
    if (c0 < cd)
      attn_compute<false>(fb, fb + 4096, ssw, qf, o, lane, quad, nl);
    else if (c0 == cd)
      attn_compute<true>(fb, fb + 4096, ssw, qf, o, lane, quad, nl);
    if (c1 < cd)
      attn_compute<false>(fb + 2048, fb + 4096 + 2048, ssw, qf, o, lane, quad, nl);
    else if (c1 == cd)
      attn_compute<true>(fb + 2048, fb + 4096 + 2048, ssw, qf, o, lane, quad, nl);
  }

#pragma unroll
  for (int m = 0; m < 2; ++m)
#pragma unroll
    for (int nb = 0; nb < 4; ++nb)
#pragma unroll
      for (int r = 0; r < 4; ++r) {
        int t = tw0 + m * 16 + quad * 4 + r;
        attnb[(size_t)(b * TT + t) * CC + h * 64 + nb * 16 + nl] = f2bf(o[m][nb][r]);
      }
}

extern "C" void kernel_launch(void* const* d_in, const int* in_sizes, int n_in,
                              void* d_out, int out_size, void* d_ws, size_t ws_size,
                              hipStream_t stream) {
  const float* x = (const float*)d_in[0];      // [4,2048,1024]
  const float* wqkv = (const float*)d_in[1];   // [3072,1024]
  const float* wout = (const float*)d_in[2];   // [1024,1024]
  float* out = (float*)d_out;                  // [4,2048,1024] fp32

  char* ws = (char*)d_ws;
  short* xb    = (short*)(ws);                  // 16.78 MB
  short* wqkvb = (short*)(ws + 16777216);       //  6.29 MB
  short* woutb = (short*)(ws + 23068672);       //  2.10 MB
  short* qkvb  = (short*)(ws + 25165824);       // 50.33 MB
  short* attnb = (short*)(ws + 75497472);       // 16.78 MB  (total 92.27 MB)
  short* vt    = xb;  // xb dead after QKV GEMM

  static bool inited = false;
  if (!inited) {  // 128 KiB dynamic LDS opt-in (not a stream op; capture-safe)
    hipFuncSetAttribute(reinterpret_cast<const void*>(&gemm256<short, 3072, 1024>),
                        hipFuncAttributeMaxDynamicSharedMemorySize, 131072);
    hipFuncSetAttribute(reinterpret_cast<const void*>(&gemm256<float, 1024, 1024>),
                        hipFuncAttributeMaxDynamicSharedMemorySize, 131072);
    inited = true;
  }

  cvt_all<<<12288, 256, 0, stream>>>(x, wqkv, wout, xb);

  gemm256<short, 3072, 1024><<<dim3(32, 12), 512, 131072, stream>>>(xb, wqkvb, qkvb);

  transpose_v<<<dim3(32, 64), 256, 0, stream>>>(qkvb, vt);

  attn_kernel<<<dim3(64, 16), 256, 0, stream>>>(qkvb, vt, attnb);

  gemm256<float, 1024, 1024><<<dim3(32, 4), 512, 131072, stream>>>(attnb, woutb, out);
}

// Round 2
// 235.916 us; speedup vs baseline: 1.0656x; 1.0305x over previous
//
#include <hip/hip_runtime.h>

#define TT 2048
#define CC 1024

typedef __attribute__((ext_vector_type(8))) __bf16 bf16x8;
typedef __attribute__((ext_vector_type(4))) float f32x4;
typedef unsigned int u32;

__device__ __forceinline__ short f2bf(float f) {
  u32 u = __float_as_uint(f);
  u += 0x7fffu + ((u >> 16) & 1u);  // RTNE
  return (short)(u >> 16);
}

#if __has_builtin(__builtin_amdgcn_cvt_pk_bf16_f32)
__device__ __forceinline__ u32 pack2(float a, float b) {
  auto v = __builtin_amdgcn_cvt_pk_bf16_f32(a, b);
  return __builtin_bit_cast(u32, v);
}
#else
__device__ __forceinline__ u32 pack2(float a, float b) {
  u32 ua = __float_as_uint(a), ub = __float_as_uint(b);
  ua += 0x7fffu + ((ua >> 16) & 1u);
  ub += 0x7fffu + ((ub >> 16) & 1u);
  return (ua >> 16) | (ub & 0xffff0000u);
}
#endif

// ---------------- fused fp32 -> bf16 cast (x | wqkv(Q scaled) | wout) ---------
__global__ __launch_bounds__(256) void cvt_all(const float* __restrict__ x,
                                               const float* __restrict__ wqkv,
                                               const float* __restrict__ wout,
                                               short* __restrict__ dst) {
  int i = blockIdx.x * blockDim.x + threadIdx.x;  // float4 index, < 3145728
  const float* src;
  float sc = 1.0f;
  if (i < 2097152) {
    src = x + (size_t)i * 4;
  } else if (i < 2883584) {
    int j = i - 2097152;
    src = wqkv + (size_t)j * 4;
    if (j < 262144) sc = 0.125f;  // Q block: fold attention scale (exact pow2)
  } else {
    src = wout + (size_t)(i - 2883584) * 4;
  }
  float4 f = *reinterpret_cast<const float4*>(src);
  short4 s;
  s.x = f2bf(f.x * sc); s.y = f2bf(f.y * sc); s.z = f2bf(f.z * sc); s.w = f2bf(f.w * sc);
  reinterpret_cast<short4*>(dst)[i] = s;
}

__device__ __forceinline__ void storev(float* p, float v) { *p = v; }
__device__ __forceinline__ void storev(short* p, float v) { *p = f2bf(v); }

#if __has_builtin(__builtin_amdgcn_global_load_lds)
#define HAVE_GLD_LDS 1
__device__ __forceinline__ void gld_lds16(const short* g, short* l) {
  __builtin_amdgcn_global_load_lds((const __attribute__((address_space(1))) u32*)g,
                                   (__attribute__((address_space(3))) u32*)l, 16, 0, 0);
}
#endif

__device__ __forceinline__ f32x4 mfma16(bf16x8 a, bf16x8 b, f32x4 c) {
  return __builtin_amdgcn_mfma_f32_16x16x32_bf16(a, b, c, 0, 0, 0);
}

template <int NN>
__device__ __forceinline__ void waitvm() {
  if constexpr (NN == 0) asm volatile("s_waitcnt vmcnt(0)" ::: "memory");
  else if constexpr (NN == 4) asm volatile("s_waitcnt vmcnt(4)" ::: "memory");
  else if constexpr (NN == 6) asm volatile("s_waitcnt vmcnt(6)" ::: "memory");
  else if constexpr (NN == 8) asm volatile("s_waitcnt vmcnt(8)" ::: "memory");
}

template <int MH, int NFR>
__device__ __forceinline__ void mmaN(f32x4 (&acc)[8][NFR], const bf16x8 (&af)[4],
                                     const bf16x8 (&bfr)[NFR]) {
#pragma unroll
  for (int mf = 0; mf < 4; ++mf)
#pragma unroll
    for (int nf = 0; nf < NFR; ++nf)
      acc[MH * 4 + mf][nf] = mfma16(af[mf], bfr[nf], acc[MH * 4 + mf][nf]);
}

// =================== C[M,N] = A[M,K] * B[N,K]^T, 256xBN 8-phase ===============
// 512 thr = 8 waves (2M x 4N), BK=64. LDS: 2 dbuf x {A[256][64], B[BN][64]}
// split in two k-panels of [rows][32] shorts (64B rows). k-slot XOR swizzle
// (slot ^= (row>>1)&3) via pre-swizzled GLOBAL source + linear global_load_lds
// dest; ds_read_b128 lands 2 dwords/bank/quarter-wave = conflict-free.
// Per-wave stage sizes: A-half = 2 glds, B-half = BGLD = BN/128 glds.
// Schedule (8 phases per iteration = 2 K-tiles; tile t -> buf[t&1]):
//   P1 rd(b0,ks0,mh0)+B   stage A(b1,ks1,2i+1)
//   P2 rd(b0,ks0,mh1)     stage B(b0,ks0,2i+2)
//   P3 rd(b0,ks1,mh0)+B   stage A(b0,ks0,2i+2)
//   P4 rd(b0,ks1,mh1)     stage B(b0,ks1,2i+2)   vmcnt(2+2*BGLD)
//   P5 rd(b1,ks0,mh0)+B   stage A(b0,ks1,2i+2)
//   P6 rd(b1,ks0,mh1)     stage B(b1,ks0,2i+3)
//   P7 rd(b1,ks1,mh0)+B   stage A(b1,ks0,2i+3)
//   P8 rd(b1,ks1,mh1)     stage B(b1,ks1,2i+3)   vmcnt(2+2*BGLD)
// Each stage target's last ds_read is in the previous phase (drained by that
// phase's lgkmcnt(0)+barrier); each consumed tile's last half is staged
// B+A+B = 2+2*BGLD loads before its vmcnt -> never drains to 0 in the loop.
#define GPHASE(DB, KS, MH, LOADB, STG, SYNC)               \
  {                                                        \
    ldA(af, DB, KS, MH);                                   \
    if (LOADB) ldB(bfr, DB, KS);                           \
    STG;                                                   \
    __builtin_amdgcn_s_barrier();                          \
    asm volatile("s_waitcnt lgkmcnt(0)" ::: "memory");     \
    __builtin_amdgcn_sched_barrier(0);                     \
    __builtin_amdgcn_s_setprio(1);                         \
    mmaN<MH>(acc, af, bfr);                                \
    __builtin_amdgcn_s_setprio(0);                         \
    SYNC;                                                  \
    __builtin_amdgcn_s_barrier();                          \
  }
#define GNOOP ((void)0)

// Grid: 1D, TM*TN tiles (TM = M/256 = 32, TN = N/BN). XCD-chunked swizzle:
// xcd = id%8 owns a contiguous 8m x RN tile region (requires TN == 2*RN),
// so its L2 sees A-panel 4.2 MB + B-panel RN*BN*2KB instead of all of A.
template <typename OutT, int N, int K, int BN, int RN>
__global__ __launch_bounds__(512, 2) void gemm8p(const short* __restrict__ A,
                                                 const short* __restrict__ B,
                                                 OutT* __restrict__ Cm) {
  constexpr int BGLD = BN / 128;        // glds per B-half stage per wave
  constexpr int NFR = BN / 64;          // B frags per wave
  constexpr int SYNCN = 2 + 2 * BGLD;   // steady-state vmcnt
  constexpr int NT = K / 64, NITER = NT / 2;
  constexpr int BHALF = BN * 32;        // shorts per B half-panel
  constexpr int DBS = 16384 + BN * 64;  // shorts per dbuf half (A pair + B pair)
  extern __shared__ short lds[];
  const int tid = threadIdx.x;
  const int wave = tid >> 6, lane = tid & 63;
  const int quad = lane >> 4, nl = lane & 15;
  const int wm = wave >> 2, wn = wave & 3;

  const int id = blockIdx.x;
  const int xcd = id & 7, slot = id >> 3;
  const int mt = (xcd & 3) * 8 + (slot & 7);
  const int nt = (xcd >> 2) * RN + (slot >> 3);
  const int m0 = mt * 256, n0 = nt * BN;

  // stage source: wave owns 32 A-rows / BN/8 B-rows; lane -> (row = L>>2, slot
  // permuted (L&3)^((L>>3)&3)); permutation stays inside 64B segs (coalesced).
  const int srow = lane >> 2;
  const int sperm = ((lane & 3) ^ ((lane >> 3) & 3)) * 8;
  const short* pA = A + (size_t)(m0 + wave * 32 + srow) * K + sperm;
  const short* pB = B + (size_t)(n0 + wave * (BN / 8) + srow) * K + sperm;

  // frag read: LDS(row, slot_lin) holds global slot (slot_lin ^ ((row>>1)&3))
  const int perm = (quad ^ ((nl >> 1) & 3)) * 8;
  const int aoff = (wm * 128 + nl) * 32 + perm;
  const int boff = (wn * (BN / 4) + nl) * 32 + perm;

  f32x4 acc[8][NFR] = {};

  auto stageA = [&](int db, int ks, int t) {
    const short* s = pA + (size_t)t * 64 + ks * 32;
    short* d = lds + db * DBS + ks * 8192 + wave * 1024;
#if HAVE_GLD_LDS
    gld_lds16(s, d);
    gld_lds16(s + (size_t)16 * K, d + 512);
#else
    *reinterpret_cast<uint4*>(d + lane * 8) = *reinterpret_cast<const uint4*>(s);
    *reinterpret_cast<uint4*>(d + 512 + lane * 8) =
        *reinterpret_cast<const uint4*>(s + (size_t)16 * K);
#endif
  };
  auto stageB = [&](int db, int ks, int t) {
    const short* s = pB + (size_t)t * 64 + ks * 32;
    short* d = lds + db * DBS + 16384 + ks * BHALF + wave * (BN * 4);
#if HAVE_GLD_LDS
    gld_lds16(s, d);
    if constexpr (BGLD == 2) gld_lds16(s + (size_t)16 * K, d + 512);
#else
    *reinterpret_cast<uint4*>(d + lane * 8) = *reinterpret_cast<const uint4*>(s);
    if constexpr (BGLD == 2)
      *reinterpret_cast<uint4*>(d + 512 + lane * 8) =
          *reinterpret_cast<const uint4*>(s + (size_t)16 * K);
#endif
  };
  auto ldA = [&](bf16x8 (&af)[4], int db, int ks, int mh) {
#pragma unroll
    for (int mf = 0; mf < 4; ++mf)
      af[mf] = *reinterpret_cast<const bf16x8*>(
          &lds[db * DBS + ks * 8192 + aoff + (mh * 4 + mf) * 512]);
  };
  auto ldB = [&](bf16x8 (&bfr)[NFR], int db, int ks) {
#pragma unroll
    for (int nf = 0; nf < NFR; ++nf)
      bfr[nf] = *reinterpret_cast<const bf16x8*>(
          &lds[db * DBS + 16384 + ks * BHALF + boff + nf * 512]);
  };

  // prologue: tile0 fully + tile1 {B_klo, A_klo, B_khi} (A_khi comes at P1).
  // After tile0's last stage (B01), later issues = B10+A10+B11 = SYNCN.
  stageA(0, 0, 0); stageA(0, 1, 0); stageB(0, 0, 0); stageB(0, 1, 0);
  stageB(1, 0, 1); stageA(1, 0, 1); stageB(1, 1, 1);
  waitvm<SYNCN>();
  __builtin_amdgcn_s_barrier();

  for (int i = 0; i < NITER - 1; ++i) {
    const int to1 = 2 * i + 1, te2 = 2 * i + 2, to3 = 2 * i + 3;
    bf16x8 af[4], bfr[NFR];
    GPHASE(0, 0, 0, 1, stageA(1, 1, to1), GNOOP)
    GPHASE(0, 0, 1, 0, stageB(0, 0, te2), GNOOP)
    GPHASE(0, 1, 0, 1, stageA(0, 0, te2), GNOOP)
    GPHASE(0, 1, 1, 0, stageB(0, 1, te2), waitvm<SYNCN>())
    GPHASE(1, 0, 0, 1, stageA(0, 1, te2), GNOOP)
    GPHASE(1, 0, 1, 0, stageB(1, 0, to3), GNOOP)
    GPHASE(1, 1, 0, 1, stageA(1, 0, to3), GNOOP)
    GPHASE(1, 1, 1, 0, stageB(1, 1, to3), waitvm<SYNCN>())
  }
  {  // last iteration: only tile NT-1's A_khi still needs staging
    bf16x8 af[4], bfr[NFR];
    GPHASE(0, 0, 0, 1, stageA(1, 1, NT - 1), GNOOP)
    GPHASE(0, 0, 1, 0, GNOOP, GNOOP)
    GPHASE(0, 1, 0, 1, GNOOP, GNOOP)
    GPHASE(0, 1, 1, 0, GNOOP, waitvm<0>())
    GPHASE(1, 0, 0, 1, GNOOP, GNOOP)
    GPHASE(1, 0, 1, 0, GNOOP, GNOOP)
    GPHASE(1, 1, 0, 1, GNOOP, GNOOP)
    GPHASE(1, 1, 1, 0, GNOOP, GNOOP)
  }

#pragma unroll
  for (int mf = 0; mf < 8; ++mf) {
    const int row = m0 + wm * 128 + mf * 16 + quad * 4;
#pragma unroll
    for (int nf = 0; nf < NFR; ++nf) {
      const int col = n0 + wn * (BN / 4) + nf * 16 + nl;
#pragma unroll
      for (int r = 0; r < 4; ++r)
        storev(&Cm[(size_t)(row + r) * N + col], acc[mf][nf][r]);
    }
  }
}

// ---------------- V transpose: qkv V-part -> Vt[bh][d][t] ---------------------
__global__ __launch_bounds__(256) void transpose_v(const short* __restrict__ qkv,
                                                   short* __restrict__ vt) {
  __shared__ short Ls[64 * 68];
  const int bh = blockIdx.y, tb = blockIdx.x;
  const int b = bh >> 4, h = bh & 15;
  const int tid = threadIdx.x;
  const short* src = qkv + (size_t)(b * TT + tb * 64) * (3 * CC) + 2 * CC + h * 64;
#pragma unroll
  for (int i = 0; i < 2; ++i) {
    int idx = tid + i * 256;
    int tl = idx >> 3, dc = idx & 7;
    uint4 d4 = *reinterpret_cast<const uint4*>(&src[(size_t)tl * (3 * CC) + dc * 8]);
    *reinterpret_cast<uint2*>(&Ls[tl * 68 + dc * 8]) = make_uint2(d4.x, d4.y);
    *reinterpret_cast<uint2*>(&Ls[tl * 68 + dc * 8 + 4]) = make_uint2(d4.z, d4.w);
  }
  __syncthreads();
  short* dst = vt + (size_t)(bh * 64) * TT + tb * 64;
#pragma unroll
  for (int i = 0; i < 2; ++i) {
    int idx = tid + i * 256;
    int dl = idx >> 3, tc = idx & 7;
    short tmp[8];
#pragma unroll
    for (int j = 0; j < 8; ++j) tmp[j] = Ls[(tc * 8 + j) * 68 + dl];
    *reinterpret_cast<uint4*>(&dst[(size_t)dl * TT + tc * 8]) = *reinterpret_cast<uint4*>(tmp);
  }
}

// ---------------- attention compute (one 32-col half-chunk, one wave) ---------
template <bool DIAG>
__device__ __forceinline__ void attn_compute(const short* kf, const short* vf, u32* ssw,
                                             const bf16x8 (&qf)[2][2], f32x4 (&o)[2][4],
                                             int lane, int quad, int nl) {
  bf16x8 k00 = *reinterpret_cast<const bf16x8*>(&kf[0 * 512 + lane * 8]);
  bf16x8 k01 = *reinterpret_cast<const bf16x8*>(&kf[1 * 512 + lane * 8]);
  bf16x8 k10 = *reinterpret_cast<const bf16x8*>(&kf[2 * 512 + lane * 8]);
  bf16x8 k11 = *reinterpret_cast<const bf16x8*>(&kf[3 * 512 + lane * 8]);
  bf16x8 vB[4];
#pragma unroll
  for (int nb = 0; nb < 4; ++nb)
    vB[nb] = *reinterpret_cast<const bf16x8*>(&vf[nb * 512 + lane * 8]);
  {
    u32* srow = &ssw[0 * 320 + nl * 20];
    f32x4 s0 = {};
    s0 = mfma16(k00, qf[0][0], s0);
    s0 = mfma16(k01, qf[0][1], s0);
    if (DIAG) {
#pragma unroll
      for (int r = 0; r < 4; ++r) s0[r] = (quad * 4 + r <= nl) ? s0[r] : 0.0f;
    }
#pragma unroll
    for (int p = 0; p < 2; ++p) srow[quad * 2 + p] = pack2(s0[2 * p], s0[2 * p + 1]);
    if (DIAG) {
#pragma unroll
      for (int p = 0; p < 2; ++p) srow[8 + quad * 2 + p] = 0;
    } else {
      f32x4 s1 = {};
      s1 = mfma16(k10, qf[0][0], s1);
      s1 = mfma16(k11, qf[0][1], s1);
#pragma unroll
      for (int p = 0; p < 2; ++p) srow[8 + quad * 2 + p] = pack2(s1[2 * p], s1[2 * p + 1]);
    }
  }
  {
    u32* srow = &ssw[1 * 320 + nl * 20];
    f32x4 s0 = {}, s1 = {};
    s0 = mfma16(k00, qf[1][0], s0);
    s0 = mfma16(k01, qf[1][1], s0);
    s1 = mfma16(k10, qf[1][0], s1);
    s1 = mfma16(k11, qf[1][1], s1);
    if (DIAG) {
#pragma unroll
      for (int r = 0; r < 4; ++r) s1[r] = (quad * 4 + r <= nl) ? s1[r] : 0.0f;
    }
#pragma unroll
    for (int p = 0; p < 2; ++p) {
      srow[quad * 2 + p] = pack2(s0[2 * p], s0[2 * p + 1]);
      srow[8 + quad * 2 + p] = pack2(s1[2 * p], s1[2 * p + 1]);
    }
  }
#pragma unroll
  for (int m = 0; m < 2; ++m) {
    bf16x8 sf = *reinterpret_cast<const bf16x8*>(&ssw[m * 320 + nl * 20 + quad * 4]);
#pragma unroll
    for (int nb = 0; nb < 4; ++nb) o[m][nb] = mfma16(sf, vB[nb], o[m][nb]);
  }
}

// ---------------- causal masked attention (no softmax) ------------------------
__global__ __launch_bounds__(256, 3) void attn_kernel(const short* __restrict__ qkv,
                                                      const short* __restrict__ vt,
                                                      short* __restrict__ attnb) {
  const int bh = blockIdx.x;
  const int b = bh >> 4, h = bh & 15;
  const int ti = 15 - blockIdx.y;  // big tiles first
  const int T0 = ti * 128;
  const int tid = threadIdx.x;
  const int wave = tid >> 6, lane = tid & 63;
  const int quad = lane >> 4, nl = lane & 15;

  const short* qbase = qkv + (size_t)(b * TT) * (3 * CC) + h * 64;
  const short* kbase = qbase + CC;
  const short* vbase = vt + (size_t)(bh * 64) * TT;

  __shared__ __align__(16) short Frag[2][8192];  // 2 x 16 KB staged K/V frags
  __shared__ __align__(16) u32 Ss[4][640];       // per-wave S roundtrip (stride 20)
  u32* ssw = Ss[wave];

  const int tw0 = T0 + wave * 32;
  bf16x8 qf[2][2];  // Q B-frags (pre-scaled by 0.125)
#pragma unroll
  for (int m = 0; m < 2; ++m)
#pragma unroll
    for (int half = 0; half < 2; ++half)
      qf[m][half] = *reinterpret_cast<const bf16x8*>(
          &qbase[(size_t)(tw0 + m * 16 + nl) * (3 * CC) + half * 32 + quad * 8]);

  f32x4 o[2][4] = {};

  const short* ksrc = kbase + (size_t)(wave * 16 + nl) * (3 * CC) + quad * 8;
  const int sp_w = wave >> 1, nb0 = (wave & 1) * 2;
  const short* vsrc0 = vbase + (size_t)((nb0 + 0) * 16 + nl) * TT + sp_w * 32 + quad * 8;
  const short* vsrc1 = vbase + (size_t)((nb0 + 1) * 16 + nl) * TT + sp_w * 32 + quad * 8;

  auto stage = [&](short* fb, int c) {
    const size_t koff = (size_t)(c * 64) * (3 * CC);
#if HAVE_GLD_LDS
    gld_lds16(ksrc + koff, &fb[(2 * wave) * 512]);
    gld_lds16(ksrc + koff + 32, &fb[(2 * wave + 1) * 512]);
    gld_lds16(vsrc0 + c * 64, &fb[4096 + (2 * wave) * 512]);
    gld_lds16(vsrc1 + c * 64, &fb[4096 + (2 * wave + 1) * 512]);
#else
    *reinterpret_cast<uint4*>(&fb[(2 * wave) * 512 + lane * 8]) =
        *reinterpret_cast<const uint4*>(ksrc + koff);
    *reinterpret_cast<uint4*>(&fb[(2 * wave + 1) * 512 + lane * 8]) =
        *reinterpret_cast<const uint4*>(ksrc + koff + 32);
    *reinterpret_cast<uint4*>(&fb[4096 + (2 * wave) * 512 + lane * 8]) =
        *reinterpret_cast<const uint4*>(vsrc0 + c * 64);
    *reinterpret_cast<uint4*>(&fb[4096 + (2 * wave + 1) * 512 + lane * 8]) =
        *reinterpret_cast<const uint4*>(vsrc1 + c * 64);
#endif
  };

  const int nch = 2 * ti + 2;     // 64-col chunks
  const int cd = 4 * ti + wave;   // this wave's diagonal 32-chunk index

  stage(Frag[0], 0);
  for (int c = 0; c < nch; ++c) {
    __syncthreads();  // compiler vmcnt(0) here drains stage(c); buf[c&1] ready
    if (c + 1 < nch) stage(Frag[(c + 1) & 1], c + 1);  // overlaps compute below
    const short* fb = Frag[c & 1];
    const int c0 = 2 * c, c1 = 2 * c + 1;
    if (c0 < cd)
      attn_compute<false>(fb, fb + 4096, ssw, qf, o, lane, quad, nl);
    else if (c0 == cd)
      attn_compute<true>(fb, fb + 4096, ssw, qf, o, lane, quad, nl);
    if (c1 < cd)
      attn_compute<false>(fb + 2048, fb + 4096 + 2048, ssw, qf, o, lane, quad, nl);
    else if (c1 == cd)
      attn_compute<true>(fb + 2048, fb + 4096 + 2048, ssw, qf, o, lane, quad, nl);
  }

#pragma unroll
  for (int m = 0; m < 2; ++m)
#pragma unroll
    for (int nb = 0; nb < 4; ++nb)
#pragma unroll
      for (int r = 0; r < 4; ++r) {
        int t = tw0 + m * 16 + quad * 4 + r;
        attnb[(size_t)(b * TT + t) * CC + h * 64 + nb * 16 + nl] = f2bf(o[m][nb][r]);
      }
}

extern "C" void kernel_launch(void* const* d_in, const int* in_sizes, int n_in,
                              void* d_out, int out_size, void* d_ws, size_t ws_size,
                              hipStream_t stream) {
  const float* x = (const float*)d_in[0];      // [4,2048,1024]
  const float* wqkv = (const float*)d_in[1];   // [3072,1024]
  const float* wout = (const float*)d_in[2];   // [1024,1024]
  float* out = (float*)d_out;                  // [4,2048,1024] fp32

  char* ws = (char*)d_ws;
  short* xb    = (short*)(ws);                  // 16.78 MB
  short* wqkvb = (short*)(ws + 16777216);       //  6.29 MB
  short* woutb = (short*)(ws + 23068672);       //  2.10 MB
  short* qkvb  = (short*)(ws + 25165824);       // 50.33 MB
  short* attnb = (short*)(ws + 75497472);       // 16.78 MB  (total 92.27 MB)
  short* vt    = xb;  // xb dead after QKV GEMM

  static bool inited = false;
  if (!inited) {  // dynamic LDS opt-in (not a stream op; capture-safe)
    hipFuncSetAttribute(reinterpret_cast<const void*>(&gemm8p<short, 3072, 1024, 256, 6>),
                        hipFuncAttributeMaxDynamicSharedMemorySize, 131072);
    hipFuncSetAttribute(reinterpret_cast<const void*>(&gemm8p<float, 1024, 1024, 128, 4>),
                        hipFuncAttributeMaxDynamicSharedMemorySize, 98304);
    inited = true;
  }

  cvt_all<<<12288, 256, 0, stream>>>(x, wqkv, wout, xb);

  // QKV: M=8192, N=3072, BN=256 -> 32x12 = 384 tiles (1.5 rounds)
  gemm8p<short, 3072, 1024, 256, 6><<<384, 512, 131072, stream>>>(xb, wqkvb, qkvb);

  transpose_v<<<dim3(32, 64), 256, 0, stream>>>(qkvb, vt);

  attn_kernel<<<dim3(64, 16), 256, 0, stream>>>(qkvb, vt, attnb);

  // out-proj: M=8192, N=1024, BN=128 -> 32x8 = 256 tiles (1 exact round)
  gemm8p<float, 1024, 1024, 128, 4><<<256, 512, 98304, stream>>>(attnb, woutb, out);
}